// Round 5
// baseline (112.083 us; speedup 1.0000x reference)
//
#include <hip/hip_runtime.h>

typedef float    v4f    __attribute__((ext_vector_type(4)));
typedef short    bf16x8 __attribute__((ext_vector_type(8)));
typedef unsigned u32x4  __attribute__((ext_vector_type(4)));
typedef unsigned short u16;

__constant__ unsigned char c_pair[28] = {
  1,2,3,4,5,6,7, 10,11,12,13,14,15, 19,20,21,22,23, 28,29,30,31, 37,38,39, 46,47, 55
};

static __device__ __forceinline__ unsigned asu(float f){ union{float f;unsigned u;}v; v.f=f; return v.u; }
static __device__ __forceinline__ float lo2f(unsigned d){ union{unsigned u;float f;}v; v.u = d<<16; return v.f; }
static __device__ __forceinline__ float hi2f(unsigned d){ union{unsigned u;float f;}v; v.u = d & 0xffff0000u; return v.f; }
static __device__ __forceinline__ unsigned pkt(float lo, float hi){
  return __builtin_amdgcn_perm(asu(hi), asu(lo), 0x07060302u);
}

// ---------------- ws image layout ----------------
#define WS_W1AB 0
#define WS_W1G  65536
#define WS_W2   98304
#define WS_GP   114688
#define WS_NEED 4308992

// ================= prep kernels =================
__global__ __launch_bounds__(1024)
void prep_weights(const float* __restrict__ W1, const float* __restrict__ W2, char* __restrict__ ws)
{
  const int idx = blockIdx.x * 1024 + threadIdx.x;   // 28 blocks * 1024 = 28672
  if (idx < 16384) {
    const int c = idx >> 6, kp = idx & 63;
    const int part = c >> 7, cc = c & 127;
    const float a  = W1[(size_t)(part * 128 + 2 * kp) * 128 + cc];
    const float b_ = W1[(size_t)(part * 128 + 2 * kp + 1) * 128 + cc];
    *(unsigned*)(ws + WS_W1AB + (size_t)c * 256 + ((kp * 4) ^ ((c & 7) << 4))) = pkt(a, b_);
  } else if (idx < 24576) {
    const int j = idx - 16384, c = j >> 6, kp = j & 63;
    const float a  = W1[(size_t)(256 + 2 * kp) * 128 + c];
    const float b_ = W1[(size_t)(256 + 2 * kp + 1) * 128 + c];
    *(unsigned*)(ws + WS_W1G + (size_t)c * 256 + ((kp * 4) ^ ((c & 7) << 4))) = pkt(a, b_);
  } else if (idx < 28672) {
    const int j = idx - 24576, c = j >> 6, kp = j & 63;
    const float a  = W2[(size_t)(2 * kp) * 64 + c];
    const float b_ = W2[(size_t)(2 * kp + 1) * 64 + c];
    *(unsigned*)(ws + WS_W2 + (size_t)c * 256 + ((kp * 4) ^ ((c & 7) << 4))) = pkt(a, b_);
  }
}

__global__ __launch_bounds__(256)
void prep_gp(const float* __restrict__ glob, const float* __restrict__ b1, char* __restrict__ ws)
{
  __shared__ __align__(16) char sm[65536];   // [0,32K) glob tile bf16 swz; [32K,64K) W1gT
  const int tid = threadIdx.x;
  const int bb0 = blockIdx.x * 128;          // 128 blocks x 128 batches
  for (int i = tid; i < 2048; i += 256) {
    const u32x4 v = *(const u32x4*)(ws + WS_W1G + i * 16);
    *(u32x4*)(sm + 32768 + i * 16) = v;
  }
  for (int i = tid; i < 4096; i += 256) {
    const int r = i >> 5, q = i & 31;
    const float4 f = *(const float4*)(glob + (size_t)(bb0 + r) * 128 + q * 4);
    int2 w; w.x = (int)pkt(f.x, f.y); w.y = (int)pkt(f.z, f.w);
    *(int2*)(sm + r * 256 + ((q * 8) ^ ((r & 7) << 4))) = w;
  }
  __syncthreads();
  const int wave = tid >> 6, lane = tid & 63, lrow = lane & 15, lko = (lane >> 4) * 8;
  float b1c[8];
#pragma unroll
  for (int nt = 0; nt < 8; ++nt) b1c[nt] = b1[nt * 16 + lrow];
  const v4f vzero = {0.f, 0.f, 0.f, 0.f};
  v4f acc[2][8];
#pragma unroll
  for (int mt = 0; mt < 2; ++mt)
#pragma unroll
    for (int nt = 0; nt < 8; ++nt) acc[mt][nt] = vzero;
#pragma unroll
  for (int ks = 0; ks < 4; ++ks) {
    const int kb = (ks * 32 + lko) * 2;
    bf16x8 af[2];
#pragma unroll
    for (int mt = 0; mt < 2; ++mt) {
      const int r = wave * 32 + mt * 16 + lrow;
      af[mt] = *(const bf16x8*)(sm + r * 256 + (kb ^ ((r & 7) << 4)));
    }
#pragma unroll
    for (int nt = 0; nt < 8; ++nt) {
      const int c = nt * 16 + lrow;
      const bf16x8 bfr = *(const bf16x8*)(sm + 32768 + c * 256 + (kb ^ ((c & 7) << 4)));
#pragma unroll
      for (int mt = 0; mt < 2; ++mt)
        acc[mt][nt] = __builtin_amdgcn_mfma_f32_16x16x32_bf16(af[mt], bfr, acc[mt][nt], 0, 0, 0);
    }
  }
#pragma unroll
  for (int mt = 0; mt < 2; ++mt)
#pragma unroll
    for (int nt = 0; nt < 8; ++nt) {
      const int c = nt * 16 + lrow;
#pragma unroll
      for (int rg = 0; rg < 4; ++rg) {
        const int m = wave * 32 + mt * 16 + (lane >> 4) * 4 + rg;
        const int batch = bb0 + m;
        const int g = batch >> 4, q = m & 15;
        *(u16*)(ws + WS_GP + (size_t)g * 4096 + q * 256 + ((c * 2) ^ ((q & 7) << 4))) =
            (u16)(asu(acc[mt][nt][rg] + b1c[nt]) >> 16);
      }
    }
}

// ================= main kernel =================
// 256 blocks (1/CU) x 1024 threads (16 waves); each block: 64 batches = 4 tiles of 16.
#define M_OFF_W   0        // 81920: W1abT rows 0..255; W2T rows at +65536
#define M_OFF_PA  81920    // 32768: node tile / Pa [128][256B]
#define M_OFF_PB  114688   // 32768: Pb [128][256B]
#define M_OFF_GP  147456   // 4096 : gp tile [16][256B]
#define M_OFF_V   151552   // 512  : b2 f32[64] | W3 f32[64]
#define M_SMEM    152064

// LDS forces 1 block/CU (152 KB) = 4 waves/SIMD; declare it so the VGPR cap is
// 512/4 = 128 instead of the compiler's default 64 (which spilled ~120 MB of
// scratch traffic per dispatch in R4).
__global__ __launch_bounds__(1024, 4)
void docking_main(const float* __restrict__ node, const int* __restrict__ dmask,
                  const float* __restrict__ b2, const float* __restrict__ W3,
                  const float* __restrict__ b3,
                  const char* __restrict__ ws, float* __restrict__ outp)
{
  __shared__ __align__(16) char smem[M_SMEM];
  const int tid = threadIdx.x;
  const int wave = tid >> 6, lane = tid & 63, lrow = lane & 15, lko = (lane >> 4) * 8;
  const int wm = wave >> 2, wn = wave & 3;
  const int bbBlk = blockIdx.x * 64;
  const float bias3 = *b3;
  const v4f vzero = {0.f, 0.f, 0.f, 0.f};

  // ---- stage weights once (pure 16B copies of pre-swizzled images) ----
  for (int i = tid; i < 4096; i += 1024) {
    const u32x4 v = *(const u32x4*)(ws + WS_W1AB + i * 16);
    *(u32x4*)(smem + M_OFF_W + i * 16) = v;
  }
  {
    const u32x4 v = *(const u32x4*)(ws + WS_W2 + tid * 16);
    *(u32x4*)(smem + M_OFF_W + 65536 + tid * 16) = v;
  }
  if (tid < 64)       ((float*)(smem + M_OFF_V))[tid] = b2[tid];
  else if (tid < 128) ((float*)(smem + M_OFF_V))[tid] = W3[tid - 64];
  __syncthreads();

  float b2n[4], w3n[4];
#pragma unroll
  for (int nt = 0; nt < 4; ++nt) {
    const int n = nt * 16 + lrow;
    b2n[nt] = ((const float*)(smem + M_OFF_V))[n];
    w3n[nt] = ((const float*)(smem + M_OFF_V))[64 + n];
  }

  for (int bt = 0; bt < 4; ++bt) {
    const int bb0 = bbBlk + bt * 16;
    // ---- stage node tile (128 rows, f32 -> bf16 swz) + gp tile (16B copies) ----
    for (int i = tid; i < 4096; i += 1024) {
      const int r = i >> 5, q = i & 31;
      const float4 f = *(const float4*)(node + ((size_t)bb0 * 8 + r) * 128 + q * 4);
      int2 w; w.x = (int)pkt(f.x, f.y); w.y = (int)pkt(f.z, f.w);
      *(int2*)(smem + M_OFF_PA + r * 256 + ((q * 8) ^ ((r & 7) << 4))) = w;
    }
    if (tid < 256) {
      const u32x4 v = *(const u32x4*)(ws + WS_GP + ((size_t)(bb0 >> 4)) * 4096 + tid * 16);
      *(u32x4*)(smem + M_OFF_GP + tid * 16) = v;
    }
    __syncthreads();                                   // (1)

    // ---- phase 1: proj GEMM  M=128 N=256 K=128, 4m x 4n wave grid ----
    v4f acc[2][4];
#pragma unroll
    for (int mt = 0; mt < 2; ++mt)
#pragma unroll
      for (int nt = 0; nt < 4; ++nt) acc[mt][nt] = vzero;
#pragma unroll
    for (int ks = 0; ks < 4; ++ks) {
      const int kb = (ks * 32 + lko) * 2;
      bf16x8 af[2];
#pragma unroll
      for (int mt = 0; mt < 2; ++mt) {
        const int r = wm * 32 + mt * 16 + lrow;
        af[mt] = *(const bf16x8*)(smem + M_OFF_PA + r * 256 + (kb ^ ((r & 7) << 4)));
      }
#pragma unroll
      for (int nt = 0; nt < 4; ++nt) {
        const int c = wn * 64 + nt * 16 + lrow;
        const bf16x8 bfr = *(const bf16x8*)(smem + M_OFF_W + c * 256 + (kb ^ ((c & 7) << 4)));
#pragma unroll
        for (int mt = 0; mt < 2; ++mt)
          acc[mt][nt] = __builtin_amdgcn_mfma_f32_16x16x32_bf16(af[mt], bfr, acc[mt][nt], 0, 0, 0);
      }
    }
    __syncthreads();                                   // (2) phase-1 reads done

    // ---- proj write: Pa (cols 0..127) over node buf, Pb (cols 128..255) ----
    {
      const int pbase = (wn >= 2) ? M_OFF_PB : M_OFF_PA;
      const int rgb = (lane >> 4) * 4;
#pragma unroll
      for (int nt = 0; nt < 4; ++nt) {
        const int c = (wn & 1) * 64 + nt * 16 + lrow;
#pragma unroll
        for (int mt = 0; mt < 2; ++mt)
#pragma unroll
          for (int rg = 0; rg < 4; ++rg) {
            const int m = wm * 32 + mt * 16 + rgb + rg;
            *(u16*)(smem + pbase + m * 256 + ((c * 2) ^ ((m & 7) << 4))) =
                (u16)(asu(acc[mt][nt][rg]) >> 16);
          }
      }
    }
    __syncthreads();                                   // (3) proj visible

    // ---- phase 2: pair MLP (28 tiles of 16 pair-rows over 16 waves) ----
    for (int t = wave; t < 28; t += 16) {
      const int r  = t * 16 + lrow;
      const int bb = (r * 9363) >> 18;                 // r/28 for r<2340
      const int p  = r - bb * 28;
      const unsigned pr8 = c_pair[p];
      const int mi = bb * 8 + (int)(pr8 >> 3);
      const int mj = bb * 8 + (int)(pr8 & 7);

      v4f acc2[4] = {vzero, vzero, vzero, vzero};
#pragma unroll
      for (int ks = 0; ks < 4; ++ks) {
        const int kb = (ks * 32 + lko) * 2;
        const u32x4 va = *(const u32x4*)(smem + M_OFF_PA + mi * 256 + (kb ^ ((mi & 7) << 4)));
        const u32x4 vb = *(const u32x4*)(smem + M_OFF_PB + mj * 256 + (kb ^ ((mj & 7) << 4)));
        const u32x4 vg = *(const u32x4*)(smem + M_OFF_GP + bb * 256 + (kb ^ ((bb & 7) << 4)));
        u32x4 a2;
#pragma unroll
        for (int w = 0; w < 4; ++w) {
          const float lo = fmaxf(lo2f(va[w]) + lo2f(vb[w]) + lo2f(vg[w]), 0.0f);
          const float hi = fmaxf(hi2f(va[w]) + hi2f(vb[w]) + hi2f(vg[w]), 0.0f);
          a2[w] = pkt(lo, hi);
        }
        union { u32x4 u; bf16x8 h; } cv; cv.u = a2;
#pragma unroll
        for (int nt = 0; nt < 4; ++nt) {
          const int cc = nt * 16 + lrow;
          const bf16x8 w2fr = *(const bf16x8*)(smem + M_OFF_W + 65536 + cc * 256 + (kb ^ ((cc & 7) << 4)));
          acc2[nt] = __builtin_amdgcn_mfma_f32_16x16x32_bf16(cv.h, w2fr, acc2[nt], 0, 0, 0);
        }
      }
      float part[4] = {0.f, 0.f, 0.f, 0.f};
#pragma unroll
      for (int nt = 0; nt < 4; ++nt)
#pragma unroll
        for (int rg = 0; rg < 4; ++rg)
          part[rg] += fmaxf(acc2[nt][rg] + b2n[nt], 0.0f) * w3n[nt];
#pragma unroll
      for (int mk = 1; mk < 16; mk <<= 1)
#pragma unroll
        for (int rg = 0; rg < 4; ++rg) part[rg] += __shfl_xor(part[rg], mk, 16);

      if ((lane & 15) == 0) {
        const int rb = t * 16 + (lane >> 4) * 4;
#pragma unroll
        for (int rg = 0; rg < 4; ++rg) {
          const int rr = rb + rg;
          const int b2_ = (rr * 9363) >> 18;
          const int p2  = rr - b2_ * 28;
          const size_t o = (size_t)(bb0 + b2_) * 28 + p2;
          outp[o] = dmask[o] ? (part[rg] + bias3) : -1.0e9f;
        }
      }
    }
    __syncthreads();                                   // (4) phase-2 reads done
  }
}

// ================= fallback (proven R3 fused kernel) =================
#define F_THREADS 512
#define F_NB      8
#define F_OFF_A    0
#define F_OFF_GL   16384
#define F_OFF_SB   20480
#define F_OFF_W2   53248
#define F_OFF_B1V  69632
#define F_OFF_B2V  70144
#define F_OFF_W3V  70400
#define F_SMEM     70656

__global__ __launch_bounds__(F_THREADS, 4)
void docking_fused(const float* __restrict__ node, const float* __restrict__ glob,
                   const int* __restrict__ dmask,
                   const float* __restrict__ W1, const float* __restrict__ b1,
                   const float* __restrict__ W2, const float* __restrict__ b2,
                   const float* __restrict__ W3, const float* __restrict__ b3,
                   float* __restrict__ outp)
{
  __shared__ __align__(16) char smem[F_SMEM];
  const int tid = threadIdx.x;
  const int bb0 = blockIdx.x * F_NB;
  const size_t nrow0 = (size_t)bb0 * 8;
  const float bias3 = *b3;

  if (tid < 128)      ((float*)(smem + F_OFF_B1V))[tid]       = b1[tid];
  else if (tid < 192) ((float*)(smem + F_OFF_B2V))[tid - 128] = b2[tid - 128];
  else if (tid < 256) ((float*)(smem + F_OFF_W3V))[tid - 192] = W3[tid - 192];

  for (int idx = tid; idx < 64 * 32; idx += F_THREADS) {
    const int r = idx >> 5, q = idx & 31;
    const float4 f = *(const float4*)(node + (nrow0 + (size_t)r) * 128 + q * 4);
    int2 w; w.x = (int)pkt(f.x, f.y); w.y = (int)pkt(f.z, f.w);
    *(int2*)(smem + F_OFF_A + r * 256 + ((q * 8) ^ ((r & 7) << 4))) = w;
  }
  for (int idx = tid; idx < 16 * 32; idx += F_THREADS) {
    const int r = idx >> 5, q = idx & 31;
    float4 f = make_float4(0.f, 0.f, 0.f, 0.f);
    if (r < F_NB) f = *(const float4*)(glob + (size_t)(bb0 + r) * 128 + q * 4);
    int2 w; w.x = (int)pkt(f.x, f.y); w.y = (int)pkt(f.z, f.w);
    *(int2*)(smem + F_OFF_GL + r * 256 + ((q * 8) ^ ((r & 7) << 4))) = w;
  }
  for (int idx = tid; idx < 4096; idx += F_THREADS) {
    const int cl = idx & 7, kl = (idx >> 3) & 7, ch = (idx >> 6) & 7, kh = idx >> 9;
    const int c = cl | (ch << 3), kp = kl | (kh << 3);
    const float a  = W2[(size_t)(2 * kp) * 64 + c];
    const float b_ = W2[(size_t)(2 * kp + 1) * 64 + c];
    *(unsigned*)(smem + F_OFF_W2 + c * 256 + ((kp * 4) ^ ((c & 7) << 4))) = pkt(a, b_);
  }
  auto stageB = [&](int rowOff) {
    for (int idx = tid; idx < 8192; idx += F_THREADS) {
      const int cl = idx & 7, kl = (idx >> 3) & 7, ch = (idx >> 6) & 15, kh = idx >> 10;
      const int c = cl | (ch << 3), kp = kl | (kh << 3);
      const float a  = W1[(size_t)(rowOff + 2 * kp) * 128 + c];
      const float b_ = W1[(size_t)(rowOff + 2 * kp + 1) * 128 + c];
      *(unsigned*)(smem + F_OFF_SB + c * 256 + ((kp * 4) ^ ((c & 7) << 4))) = pkt(a, b_);
    }
  };
  stageB(0);
  __syncthreads();

  const int wave = tid >> 6, lane = tid & 63;
  const int lrow = lane & 15;
  const int lko  = (lane >> 4) * 8;
  const int wmt = wave >> 1, wnh = wave & 1;
  const v4f vzero = {0.f, 0.f, 0.f, 0.f};

  bf16x8 af[4];
#pragma unroll
  for (int ks = 0; ks < 4; ++ks) {
    const int r = wmt * 16 + lrow;
    af[ks] = *(const bf16x8*)(smem + F_OFF_A + r * 256 + (((ks * 32 + lko) * 2) ^ ((r & 7) << 4)));
  }
  v4f acc_a[4] = {vzero, vzero, vzero, vzero};
#pragma unroll
  for (int ks = 0; ks < 4; ++ks) {
    const int kb = (ks * 32 + lko) * 2;
#pragma unroll
    for (int nt = 0; nt < 4; ++nt) {
      const int c = wnh * 64 + nt * 16 + lrow;
      const bf16x8 bfr = *(const bf16x8*)(smem + F_OFF_SB + c * 256 + (kb ^ ((c & 7) << 4)));
      acc_a[nt] = __builtin_amdgcn_mfma_f32_16x16x32_bf16(af[ks], bfr, acc_a[nt], 0, 0, 0);
    }
  }
  __syncthreads();
  stageB(128);
  __syncthreads();
  v4f acc_b[4] = {vzero, vzero, vzero, vzero};
#pragma unroll
  for (int ks = 0; ks < 4; ++ks) {
    const int kb = (ks * 32 + lko) * 2;
#pragma unroll
    for (int nt = 0; nt < 4; ++nt) {
      const int c = wnh * 64 + nt * 16 + lrow;
      const bf16x8 bfr = *(const bf16x8*)(smem + F_OFF_SB + c * 256 + (kb ^ ((c & 7) << 4)));
      acc_b[nt] = __builtin_amdgcn_mfma_f32_16x16x32_bf16(af[ks], bfr, acc_b[nt], 0, 0, 0);
    }
  }
  __syncthreads();
  stageB(256);
  __syncthreads();
  v4f accg = vzero;
#pragma unroll
  for (int ks = 0; ks < 4; ++ks) {
    const int kb = (ks * 32 + lko) * 2;
    const bf16x8 ag = *(const bf16x8*)(smem + F_OFF_GL + lrow * 256 + (kb ^ ((lrow & 7) << 4)));
    const int cg = wave * 16 + lrow;
    const bf16x8 bg = *(const bf16x8*)(smem + F_OFF_SB + cg * 256 + (kb ^ ((cg & 7) << 4)));
    accg = __builtin_amdgcn_mfma_f32_16x16x32_bf16(ag, bg, accg, 0, 0, 0);
  }
  __syncthreads();
  {
    const int rgb = (lane >> 4) * 4;
#pragma unroll
    for (int nt = 0; nt < 4; ++nt) {
      const int c = wnh * 64 + nt * 16 + lrow;
#pragma unroll
      for (int rg = 0; rg < 4; ++rg) {
        const int m = wmt * 16 + rgb + rg;
        const int sw = (c * 2) ^ ((m & 7) << 4);
        *(u16*)(smem + F_OFF_SB + m * 256 + sw)        = (u16)(asu(acc_a[nt][rg]) >> 16);
        *(u16*)(smem + F_OFF_SB + (64 + m) * 256 + sw) = (u16)(asu(acc_b[nt][rg]) >> 16);
      }
    }
    const int cg = wave * 16 + lrow;
    const float b1c = ((const float*)(smem + F_OFF_B1V))[cg];
#pragma unroll
    for (int rg = 0; rg < 4; ++rg) {
      const int bbr = rgb + rg;
      if (bbr < F_NB)
        *(u16*)(smem + F_OFF_A + bbr * 256 + ((cg * 2) ^ ((bbr & 7) << 4))) =
            (u16)(asu(accg[rg] + b1c) >> 16);
    }
  }
  __syncthreads();

  float b2n[4], w3n[4];
#pragma unroll
  for (int nt = 0; nt < 4; ++nt) {
    const int n = nt * 16 + lrow;
    b2n[nt] = ((const float*)(smem + F_OFF_B2V))[n];
    w3n[nt] = ((const float*)(smem + F_OFF_W3V))[n];
  }
  for (int t = wave; t < 14; t += 8) {
    const int r  = t * 16 + lrow;
    const int bb = (r * 9363) >> 18;
    const int p  = r - bb * 28;
    const unsigned pr8 = c_pair[p];
    const int mi = bb * 8 + (int)(pr8 >> 3);
    const int mj = 64 + bb * 8 + (int)(pr8 & 7);
    v4f acc2[4] = {vzero, vzero, vzero, vzero};
#pragma unroll
    for (int ks = 0; ks < 4; ++ks) {
      const int kb = (ks * 32 + lko) * 2;
      const u32x4 va = *(const u32x4*)(smem + F_OFF_SB + mi * 256 + (kb ^ ((mi & 7) << 4)));
      const u32x4 vb = *(const u32x4*)(smem + F_OFF_SB + mj * 256 + (kb ^ ((mj & 7) << 4)));
      const u32x4 vg = *(const u32x4*)(smem + F_OFF_A  + bb * 256 + (kb ^ ((bb & 7) << 4)));
      u32x4 a2;
#pragma unroll
      for (int w = 0; w < 4; ++w) {
        const float lo = fmaxf(lo2f(va[w]) + lo2f(vb[w]) + lo2f(vg[w]), 0.0f);
        const float hi = fmaxf(hi2f(va[w]) + hi2f(vb[w]) + hi2f(vg[w]), 0.0f);
        a2[w] = pkt(lo, hi);
      }
      union { u32x4 u; bf16x8 h; } cv; cv.u = a2;
#pragma unroll
      for (int nt = 0; nt < 4; ++nt) {
        const int c = nt * 16 + lrow;
        const bf16x8 w2fr = *(const bf16x8*)(smem + F_OFF_W2 + c * 256 + (kb ^ ((c & 7) << 4)));
        acc2[nt] = __builtin_amdgcn_mfma_f32_16x16x32_bf16(cv.h, w2fr, acc2[nt], 0, 0, 0);
      }
    }
    float part[4] = {0.f, 0.f, 0.f, 0.f};
#pragma unroll
    for (int nt = 0; nt < 4; ++nt)
#pragma unroll
      for (int rg = 0; rg < 4; ++rg)
        part[rg] += fmaxf(acc2[nt][rg] + b2n[nt], 0.0f) * w3n[nt];
#pragma unroll
    for (int mk = 1; mk < 16; mk <<= 1)
#pragma unroll
      for (int rg = 0; rg < 4; ++rg) part[rg] += __shfl_xor(part[rg], mk, 16);
    if ((lane & 15) == 0) {
      const int rb = t * 16 + (lane >> 4) * 4;
#pragma unroll
      for (int rg = 0; rg < 4; ++rg) {
        const int rr = rb + rg;
        const int b2_ = (rr * 9363) >> 18;
        const int p2  = rr - b2_ * 28;
        const size_t o = (size_t)(bb0 + b2_) * 28 + p2;
        outp[o] = dmask[o] ? (part[rg] + bias3) : -1.0e9f;
      }
    }
  }
}

extern "C" void kernel_launch(void* const* d_in, const int* in_sizes, int n_in,
                              void* d_out, int out_size, void* d_ws, size_t ws_size,
                              hipStream_t stream) {
  (void)in_sizes; (void)n_in; (void)out_size;
  const float* node = (const float*)d_in[0];
  const float* glob = (const float*)d_in[1];
  const int* dmsk   = (const int*)d_in[3];   // bool -> int32 on upload
  const float* W1 = (const float*)d_in[5];
  const float* b1 = (const float*)d_in[6];
  const float* W2 = (const float*)d_in[7];
  const float* b2 = (const float*)d_in[8];
  const float* W3 = (const float*)d_in[9];
  const float* b3 = (const float*)d_in[10];
  float* outp = (float*)d_out;

  if (ws_size >= (size_t)WS_NEED) {
    char* ws = (char*)d_ws;
    prep_weights<<<28, 1024, 0, stream>>>(W1, W2, ws);
    prep_gp<<<128, 256, 0, stream>>>(glob, b1, ws);
    docking_main<<<256, 1024, 0, stream>>>(node, dmsk, b2, W3, b3, ws, outp);
  } else {
    docking_fused<<<16384 / F_NB, F_THREADS, 0, stream>>>(node, glob, dmsk, W1, b1, W2, b2, W3, b3, outp);
  }
}

// Round 6
// 92.898 us; speedup vs baseline: 1.2065x; 1.2065x over previous
//
#include <hip/hip_runtime.h>

typedef float    v4f    __attribute__((ext_vector_type(4)));
typedef short    bf16x8 __attribute__((ext_vector_type(8)));
typedef unsigned u32x4  __attribute__((ext_vector_type(4)));
typedef unsigned short u16;

__constant__ unsigned char c_pair[28] = {
  1,2,3,4,5,6,7, 10,11,12,13,14,15, 19,20,21,22,23, 28,29,30,31, 37,38,39, 46,47, 55
};

static __device__ __forceinline__ unsigned asu(float f){ union{float f;unsigned u;}v; v.f=f; return v.u; }
static __device__ __forceinline__ float lo2f(unsigned d){ union{unsigned u;float f;}v; v.u = d<<16; return v.f; }
static __device__ __forceinline__ float hi2f(unsigned d){ union{unsigned u;float f;}v; v.u = d & 0xffff0000u; return v.f; }
static __device__ __forceinline__ unsigned pkt(float lo, float hi){
  return __builtin_amdgcn_perm(asu(hi), asu(lo), 0x07060302u);
}

// ---------------- ws image layout ----------------
#define WS_W1AB 0
#define WS_W1G  65536
#define WS_W2   98304
#define WS_GP   114688
#define WS_NEED 4308992

// ================= prep kernels =================
__global__ __launch_bounds__(1024)
void prep_weights(const float* __restrict__ W1, const float* __restrict__ W2, char* __restrict__ ws)
{
  const int idx = blockIdx.x * 1024 + threadIdx.x;   // 28 blocks * 1024 = 28672
  if (idx < 16384) {
    const int c = idx >> 6, kp = idx & 63;
    const int part = c >> 7, cc = c & 127;
    const float a  = W1[(size_t)(part * 128 + 2 * kp) * 128 + cc];
    const float b_ = W1[(size_t)(part * 128 + 2 * kp + 1) * 128 + cc];
    *(unsigned*)(ws + WS_W1AB + (size_t)c * 256 + ((kp * 4) ^ ((c & 7) << 4))) = pkt(a, b_);
  } else if (idx < 24576) {
    const int j = idx - 16384, c = j >> 6, kp = j & 63;
    const float a  = W1[(size_t)(256 + 2 * kp) * 128 + c];
    const float b_ = W1[(size_t)(256 + 2 * kp + 1) * 128 + c];
    *(unsigned*)(ws + WS_W1G + (size_t)c * 256 + ((kp * 4) ^ ((c & 7) << 4))) = pkt(a, b_);
  } else if (idx < 28672) {
    const int j = idx - 24576, c = j >> 6, kp = j & 63;
    const float a  = W2[(size_t)(2 * kp) * 64 + c];
    const float b_ = W2[(size_t)(2 * kp + 1) * 64 + c];
    *(unsigned*)(ws + WS_W2 + (size_t)c * 256 + ((kp * 4) ^ ((c & 7) << 4))) = pkt(a, b_);
  }
}

__global__ __launch_bounds__(256)
void prep_gp(const float* __restrict__ glob, const float* __restrict__ b1, char* __restrict__ ws)
{
  __shared__ __align__(16) char sm[65536];   // [0,32K) glob tile bf16 swz; [32K,64K) W1gT
  const int tid = threadIdx.x;
  const int bb0 = blockIdx.x * 128;          // 128 blocks x 128 batches
  for (int i = tid; i < 2048; i += 256) {
    const u32x4 v = *(const u32x4*)(ws + WS_W1G + i * 16);
    *(u32x4*)(sm + 32768 + i * 16) = v;
  }
  for (int i = tid; i < 4096; i += 256) {
    const int r = i >> 5, q = i & 31;
    const float4 f = *(const float4*)(glob + (size_t)(bb0 + r) * 128 + q * 4);
    int2 w; w.x = (int)pkt(f.x, f.y); w.y = (int)pkt(f.z, f.w);
    *(int2*)(sm + r * 256 + ((q * 8) ^ ((r & 7) << 4))) = w;
  }
  __syncthreads();
  const int wave = tid >> 6, lane = tid & 63, lrow = lane & 15, lko = (lane >> 4) * 8;
  float b1c[8];
#pragma unroll
  for (int nt = 0; nt < 8; ++nt) b1c[nt] = b1[nt * 16 + lrow];
  const v4f vzero = {0.f, 0.f, 0.f, 0.f};
  v4f acc[2][8];
#pragma unroll
  for (int mt = 0; mt < 2; ++mt)
#pragma unroll
    for (int nt = 0; nt < 8; ++nt) acc[mt][nt] = vzero;
#pragma unroll
  for (int ks = 0; ks < 4; ++ks) {
    const int kb = (ks * 32 + lko) * 2;
    bf16x8 af[2];
#pragma unroll
    for (int mt = 0; mt < 2; ++mt) {
      const int r = wave * 32 + mt * 16 + lrow;
      af[mt] = *(const bf16x8*)(sm + r * 256 + (kb ^ ((r & 7) << 4)));
    }
#pragma unroll
    for (int nt = 0; nt < 8; ++nt) {
      const int c = nt * 16 + lrow;
      const bf16x8 bfr = *(const bf16x8*)(sm + 32768 + c * 256 + (kb ^ ((c & 7) << 4)));
#pragma unroll
      for (int mt = 0; mt < 2; ++mt)
        acc[mt][nt] = __builtin_amdgcn_mfma_f32_16x16x32_bf16(af[mt], bfr, acc[mt][nt], 0, 0, 0);
    }
  }
#pragma unroll
  for (int mt = 0; mt < 2; ++mt)
#pragma unroll
    for (int nt = 0; nt < 8; ++nt) {
      const int c = nt * 16 + lrow;
#pragma unroll
      for (int rg = 0; rg < 4; ++rg) {
        const int m = wave * 32 + mt * 16 + (lane >> 4) * 4 + rg;
        const int batch = bb0 + m;
        const int g = batch >> 4, q = m & 15;
        *(u16*)(ws + WS_GP + (size_t)g * 4096 + q * 256 + ((c * 2) ^ ((q & 7) << 4))) =
            (u16)(asu(acc[mt][nt][rg] + b1c[nt]) >> 16);
      }
    }
}

// ================= main kernel =================
// 256 blocks (1/CU) x 1024 threads (16 waves); each block: 64 batches = 4 tiles of 16.
#define M_OFF_W   0        // 81920: W1abT rows 0..255; W2T rows at +65536
#define M_OFF_PA  81920    // 32768: node tile / Pa [128][256B]
#define M_OFF_PB  114688   // 32768: Pb [128][256B]
#define M_OFF_GP  147456   // 4096 : gp tile [16][256B]
#define M_OFF_V   151552   // 512  : b2 f32[64] | W3 f32[64]
#define M_SMEM    152064

// LDS (152 KB) forces 1 block/CU = 4 waves/SIMD. Pin that via amdgpu_waves_per_eu
// so the VGPR budget is 512/4 = 128 (the default heuristic capped at 64 and spilled
// ~120 MB/dispatch of scratch traffic in R4/R5; __launch_bounds__(1024,4) was a no-op).
__global__ __attribute__((amdgpu_flat_work_group_size(1024, 1024), amdgpu_waves_per_eu(4, 4)))
void docking_main(const float* __restrict__ node, const int* __restrict__ dmask,
                  const float* __restrict__ b2, const float* __restrict__ W3,
                  const float* __restrict__ b3,
                  const char* __restrict__ ws, float* __restrict__ outp)
{
  __shared__ __align__(16) char smem[M_SMEM];
  const int tid = threadIdx.x;
  const int wave = tid >> 6, lane = tid & 63, lrow = lane & 15, lko = (lane >> 4) * 8;
  const int wm = wave >> 2, wn = wave & 3;
  const int bbBlk = blockIdx.x * 64;
  const float bias3 = *b3;
  const v4f vzero = {0.f, 0.f, 0.f, 0.f};

  // ---- stage weights once (pure 16B copies of pre-swizzled images) ----
  for (int i = tid; i < 4096; i += 1024) {
    const u32x4 v = *(const u32x4*)(ws + WS_W1AB + i * 16);
    *(u32x4*)(smem + M_OFF_W + i * 16) = v;
  }
  {
    const u32x4 v = *(const u32x4*)(ws + WS_W2 + tid * 16);
    *(u32x4*)(smem + M_OFF_W + 65536 + tid * 16) = v;
  }
  if (tid < 64)       ((float*)(smem + M_OFF_V))[tid] = b2[tid];
  else if (tid < 128) ((float*)(smem + M_OFF_V))[tid] = W3[tid - 64];
  __syncthreads();

  float b2n[4], w3n[4];
#pragma unroll
  for (int nt = 0; nt < 4; ++nt) {
    const int n = nt * 16 + lrow;
    b2n[nt] = ((const float*)(smem + M_OFF_V))[n];
    w3n[nt] = ((const float*)(smem + M_OFF_V))[64 + n];
  }

  for (int bt = 0; bt < 4; ++bt) {
    const int bb0 = bbBlk + bt * 16;
    // ---- stage node tile (128 rows, f32 -> bf16 swz) + gp tile (16B copies) ----
    for (int i = tid; i < 4096; i += 1024) {
      const int r = i >> 5, q = i & 31;
      const float4 f = *(const float4*)(node + ((size_t)bb0 * 8 + r) * 128 + q * 4);
      int2 w; w.x = (int)pkt(f.x, f.y); w.y = (int)pkt(f.z, f.w);
      *(int2*)(smem + M_OFF_PA + r * 256 + ((q * 8) ^ ((r & 7) << 4))) = w;
    }
    if (tid < 256) {
      const u32x4 v = *(const u32x4*)(ws + WS_GP + ((size_t)(bb0 >> 4)) * 4096 + tid * 16);
      *(u32x4*)(smem + M_OFF_GP + tid * 16) = v;
    }
    __syncthreads();                                   // (1) tile staged

    // ---- preload this wave's A-fragments for the whole K (32 VGPRs) ----
    bf16x8 af[2][4];
#pragma unroll
    for (int mt = 0; mt < 2; ++mt)
#pragma unroll
      for (int ks = 0; ks < 4; ++ks) {
        const int r = wm * 32 + mt * 16 + lrow;
        af[mt][ks] = *(const bf16x8*)(smem + M_OFF_PA + r * 256 + (((ks * 32 + lko) * 2) ^ ((r & 7) << 4)));
      }
    __syncthreads();                                   // (2) node buffer now dead

    // ---- phase 1: proj GEMM in two N-halves (acc live range = 16 regs) ----
#pragma unroll 1
    for (int half = 0; half < 2; ++half) {
      v4f acc[2][2];
#pragma unroll
      for (int mt = 0; mt < 2; ++mt)
#pragma unroll
        for (int nt = 0; nt < 2; ++nt) acc[mt][nt] = vzero;
#pragma unroll
      for (int ks = 0; ks < 4; ++ks) {
        const int kb = (ks * 32 + lko) * 2;
#pragma unroll
        for (int nt = 0; nt < 2; ++nt) {
          const int c = wn * 64 + (half * 2 + nt) * 16 + lrow;
          const bf16x8 bfr = *(const bf16x8*)(smem + M_OFF_W + c * 256 + (kb ^ ((c & 7) << 4)));
#pragma unroll
          for (int mt = 0; mt < 2; ++mt)
            acc[mt][nt] = __builtin_amdgcn_mfma_f32_16x16x32_bf16(af[mt][ks], bfr, acc[mt][nt], 0, 0, 0);
        }
      }
      // write immediately: wn<2 -> Pa (over node buf, safe after (2)); wn>=2 -> Pb
      const int pbase = (wn >= 2) ? M_OFF_PB : M_OFF_PA;
      const int rgb = (lane >> 4) * 4;
#pragma unroll
      for (int nt = 0; nt < 2; ++nt) {
        const int c = (wn & 1) * 64 + (half * 2 + nt) * 16 + lrow;
#pragma unroll
        for (int mt = 0; mt < 2; ++mt)
#pragma unroll
          for (int rg = 0; rg < 4; ++rg) {
            const int m = wm * 32 + mt * 16 + rgb + rg;
            *(u16*)(smem + pbase + m * 256 + ((c * 2) ^ ((m & 7) << 4))) =
                (u16)(asu(acc[mt][nt][rg]) >> 16);
          }
      }
    }
    __syncthreads();                                   // (3) proj visible

    // ---- phase 2: pair MLP (28 tiles of 16 pair-rows over 16 waves) ----
    for (int t = wave; t < 28; t += 16) {
      const int r  = t * 16 + lrow;
      const int bb = (r * 9363) >> 18;                 // r/28 for r<2340
      const int p  = r - bb * 28;
      const unsigned pr8 = c_pair[p];
      const int mi = bb * 8 + (int)(pr8 >> 3);
      const int mj = bb * 8 + (int)(pr8 & 7);

      v4f acc2[4] = {vzero, vzero, vzero, vzero};
#pragma unroll
      for (int ks = 0; ks < 4; ++ks) {
        const int kb = (ks * 32 + lko) * 2;
        const u32x4 va = *(const u32x4*)(smem + M_OFF_PA + mi * 256 + (kb ^ ((mi & 7) << 4)));
        const u32x4 vb = *(const u32x4*)(smem + M_OFF_PB + mj * 256 + (kb ^ ((mj & 7) << 4)));
        const u32x4 vg = *(const u32x4*)(smem + M_OFF_GP + bb * 256 + (kb ^ ((bb & 7) << 4)));
        u32x4 a2;
#pragma unroll
        for (int w = 0; w < 4; ++w) {
          const float lo = fmaxf(lo2f(va[w]) + lo2f(vb[w]) + lo2f(vg[w]), 0.0f);
          const float hi = fmaxf(hi2f(va[w]) + hi2f(vb[w]) + hi2f(vg[w]), 0.0f);
          a2[w] = pkt(lo, hi);
        }
        union { u32x4 u; bf16x8 h; } cv; cv.u = a2;
#pragma unroll
        for (int nt = 0; nt < 4; ++nt) {
          const int cc = nt * 16 + lrow;
          const bf16x8 w2fr = *(const bf16x8*)(smem + M_OFF_W + 65536 + cc * 256 + (kb ^ ((cc & 7) << 4)));
          acc2[nt] = __builtin_amdgcn_mfma_f32_16x16x32_bf16(cv.h, w2fr, acc2[nt], 0, 0, 0);
        }
      }
      float part[4] = {0.f, 0.f, 0.f, 0.f};
#pragma unroll
      for (int nt = 0; nt < 4; ++nt)
#pragma unroll
        for (int rg = 0; rg < 4; ++rg)
          part[rg] += fmaxf(acc2[nt][rg] + b2n[nt], 0.0f) * w3n[nt];
#pragma unroll
      for (int mk = 1; mk < 16; mk <<= 1)
#pragma unroll
        for (int rg = 0; rg < 4; ++rg) part[rg] += __shfl_xor(part[rg], mk, 16);

      if ((lane & 15) == 0) {
        const int rb = t * 16 + (lane >> 4) * 4;
#pragma unroll
        for (int rg = 0; rg < 4; ++rg) {
          const int rr = rb + rg;
          const int b2_ = (rr * 9363) >> 18;
          const int p2  = rr - b2_ * 28;
          const size_t o = (size_t)(bb0 + b2_) * 28 + p2;
          outp[o] = dmask[o] ? (part[rg] + bias3) : -1.0e9f;
        }
      }
    }
    __syncthreads();                                   // (4) phase-2 reads done
  }
}

// ================= fallback (proven R3 fused kernel) =================
#define F_THREADS 512
#define F_NB      8
#define F_OFF_A    0
#define F_OFF_GL   16384
#define F_OFF_SB   20480
#define F_OFF_W2   53248
#define F_OFF_B1V  69632
#define F_OFF_B2V  70144
#define F_OFF_W3V  70400
#define F_SMEM     70656

__global__ __launch_bounds__(F_THREADS, 4)
void docking_fused(const float* __restrict__ node, const float* __restrict__ glob,
                   const int* __restrict__ dmask,
                   const float* __restrict__ W1, const float* __restrict__ b1,
                   const float* __restrict__ W2, const float* __restrict__ b2,
                   const float* __restrict__ W3, const float* __restrict__ b3,
                   float* __restrict__ outp)
{
  __shared__ __align__(16) char smem[F_SMEM];
  const int tid = threadIdx.x;
  const int bb0 = blockIdx.x * F_NB;
  const size_t nrow0 = (size_t)bb0 * 8;
  const float bias3 = *b3;

  if (tid < 128)      ((float*)(smem + F_OFF_B1V))[tid]       = b1[tid];
  else if (tid < 192) ((float*)(smem + F_OFF_B2V))[tid - 128] = b2[tid - 128];
  else if (tid < 256) ((float*)(smem + F_OFF_W3V))[tid - 192] = W3[tid - 192];

  for (int idx = tid; idx < 64 * 32; idx += F_THREADS) {
    const int r = idx >> 5, q = idx & 31;
    const float4 f = *(const float4*)(node + (nrow0 + (size_t)r) * 128 + q * 4);
    int2 w; w.x = (int)pkt(f.x, f.y); w.y = (int)pkt(f.z, f.w);
    *(int2*)(smem + F_OFF_A + r * 256 + ((q * 8) ^ ((r & 7) << 4))) = w;
  }
  for (int idx = tid; idx < 16 * 32; idx += F_THREADS) {
    const int r = idx >> 5, q = idx & 31;
    float4 f = make_float4(0.f, 0.f, 0.f, 0.f);
    if (r < F_NB) f = *(const float4*)(glob + (size_t)(bb0 + r) * 128 + q * 4);
    int2 w; w.x = (int)pkt(f.x, f.y); w.y = (int)pkt(f.z, f.w);
    *(int2*)(smem + F_OFF_GL + r * 256 + ((q * 8) ^ ((r & 7) << 4))) = w;
  }
  for (int idx = tid; idx < 4096; idx += F_THREADS) {
    const int cl = idx & 7, kl = (idx >> 3) & 7, ch = (idx >> 6) & 7, kh = idx >> 9;
    const int c = cl | (ch << 3), kp = kl | (kh << 3);
    const float a  = W2[(size_t)(2 * kp) * 64 + c];
    const float b_ = W2[(size_t)(2 * kp + 1) * 64 + c];
    *(unsigned*)(smem + F_OFF_W2 + c * 256 + ((kp * 4) ^ ((c & 7) << 4))) = pkt(a, b_);
  }
  auto stageB = [&](int rowOff) {
    for (int idx = tid; idx < 8192; idx += F_THREADS) {
      const int cl = idx & 7, kl = (idx >> 3) & 7, ch = (idx >> 6) & 15, kh = idx >> 10;
      const int c = cl | (ch << 3), kp = kl | (kh << 3);
      const float a  = W1[(size_t)(rowOff + 2 * kp) * 128 + c];
      const float b_ = W1[(size_t)(rowOff + 2 * kp + 1) * 128 + c];
      *(unsigned*)(smem + F_OFF_SB + c * 256 + ((kp * 4) ^ ((c & 7) << 4))) = pkt(a, b_);
    }
  };
  stageB(0);
  __syncthreads();

  const int wave = tid >> 6, lane = tid & 63;
  const int lrow = lane & 15;
  const int lko  = (lane >> 4) * 8;
  const int wmt = wave >> 1, wnh = wave & 1;
  const v4f vzero = {0.f, 0.f, 0.f, 0.f};

  bf16x8 af[4];
#pragma unroll
  for (int ks = 0; ks < 4; ++ks) {
    const int r = wmt * 16 + lrow;
    af[ks] = *(const bf16x8*)(smem + F_OFF_A + r * 256 + (((ks * 32 + lko) * 2) ^ ((r & 7) << 4)));
  }
  v4f acc_a[4] = {vzero, vzero, vzero, vzero};
#pragma unroll
  for (int ks = 0; ks < 4; ++ks) {
    const int kb = (ks * 32 + lko) * 2;
#pragma unroll
    for (int nt = 0; nt < 4; ++nt) {
      const int c = wnh * 64 + nt * 16 + lrow;
      const bf16x8 bfr = *(const bf16x8*)(smem + F_OFF_SB + c * 256 + (kb ^ ((c & 7) << 4)));
      acc_a[nt] = __builtin_amdgcn_mfma_f32_16x16x32_bf16(af[ks], bfr, acc_a[nt], 0, 0, 0);
    }
  }
  __syncthreads();
  stageB(128);
  __syncthreads();
  v4f acc_b[4] = {vzero, vzero, vzero, vzero};
#pragma unroll
  for (int ks = 0; ks < 4; ++ks) {
    const int kb = (ks * 32 + lko) * 2;
#pragma unroll
    for (int nt = 0; nt < 4; ++nt) {
      const int c = wnh * 64 + nt * 16 + lrow;
      const bf16x8 bfr = *(const bf16x8*)(smem + F_OFF_SB + c * 256 + (kb ^ ((c & 7) << 4)));
      acc_b[nt] = __builtin_amdgcn_mfma_f32_16x16x32_bf16(af[ks], bfr, acc_b[nt], 0, 0, 0);
    }
  }
  __syncthreads();
  stageB(256);
  __syncthreads();
  v4f accg = vzero;
#pragma unroll
  for (int ks = 0; ks < 4; ++ks) {
    const int kb = (ks * 32 + lko) * 2;
    const bf16x8 ag = *(const bf16x8*)(smem + F_OFF_GL + lrow * 256 + (kb ^ ((lrow & 7) << 4)));
    const int cg = wave * 16 + lrow;
    const bf16x8 bg = *(const bf16x8*)(smem + F_OFF_SB + cg * 256 + (kb ^ ((cg & 7) << 4)));
    accg = __builtin_amdgcn_mfma_f32_16x16x32_bf16(ag, bg, accg, 0, 0, 0);
  }
  __syncthreads();
  {
    const int rgb = (lane >> 4) * 4;
#pragma unroll
    for (int nt = 0; nt < 4; ++nt) {
      const int c = wnh * 64 + nt * 16 + lrow;
#pragma unroll
      for (int rg = 0; rg < 4; ++rg) {
        const int m = wmt * 16 + rgb + rg;
        const int sw = (c * 2) ^ ((m & 7) << 4);
        *(u16*)(smem + F_OFF_SB + m * 256 + sw)        = (u16)(asu(acc_a[nt][rg]) >> 16);
        *(u16*)(smem + F_OFF_SB + (64 + m) * 256 + sw) = (u16)(asu(acc_b[nt][rg]) >> 16);
      }
    }
    const int cg = wave * 16 + lrow;
    const float b1c = ((const float*)(smem + F_OFF_B1V))[cg];
#pragma unroll
    for (int rg = 0; rg < 4; ++rg) {
      const int bbr = rgb + rg;
      if (bbr < F_NB)
        *(u16*)(smem + F_OFF_A + bbr * 256 + ((cg * 2) ^ ((bbr & 7) << 4))) =
            (u16)(asu(accg[rg] + b1c) >> 16);
    }
  }
  __syncthreads();

  float b2n[4], w3n[4];
#pragma unroll
  for (int nt = 0; nt < 4; ++nt) {
    const int n = nt * 16 + lrow;
    b2n[nt] = ((const float*)(smem + F_OFF_B2V))[n];
    w3n[nt] = ((const float*)(smem + F_OFF_W3V))[n];
  }
  for (int t = wave; t < 14; t += 8) {
    const int r  = t * 16 + lrow;
    const int bb = (r * 9363) >> 18;
    const int p  = r - bb * 28;
    const unsigned pr8 = c_pair[p];
    const int mi = bb * 8 + (int)(pr8 >> 3);
    const int mj = 64 + bb * 8 + (int)(pr8 & 7);
    v4f acc2[4] = {vzero, vzero, vzero, vzero};
#pragma unroll
    for (int ks = 0; ks < 4; ++ks) {
      const int kb = (ks * 32 + lko) * 2;
      const u32x4 va = *(const u32x4*)(smem + F_OFF_SB + mi * 256 + (kb ^ ((mi & 7) << 4)));
      const u32x4 vb = *(const u32x4*)(smem + F_OFF_SB + mj * 256 + (kb ^ ((mj & 7) << 4)));
      const u32x4 vg = *(const u32x4*)(smem + F_OFF_A  + bb * 256 + (kb ^ ((bb & 7) << 4)));
      u32x4 a2;
#pragma unroll
      for (int w = 0; w < 4; ++w) {
        const float lo = fmaxf(lo2f(va[w]) + lo2f(vb[w]) + lo2f(vg[w]), 0.0f);
        const float hi = fmaxf(hi2f(va[w]) + hi2f(vb[w]) + hi2f(vg[w]), 0.0f);
        a2[w] = pkt(lo, hi);
      }
      union { u32x4 u; bf16x8 h; } cv; cv.u = a2;
#pragma unroll
      for (int nt = 0; nt < 4; ++nt) {
        const int c = nt * 16 + lrow;
        const bf16x8 w2fr = *(const bf16x8*)(smem + F_OFF_W2 + c * 256 + (kb ^ ((c & 7) << 4)));
        acc2[nt] = __builtin_amdgcn_mfma_f32_16x16x32_bf16(cv.h, w2fr, acc2[nt], 0, 0, 0);
      }
    }
    float part[4] = {0.f, 0.f, 0.f, 0.f};
#pragma unroll
    for (int nt = 0; nt < 4; ++nt)
#pragma unroll
      for (int rg = 0; rg < 4; ++rg)
        part[rg] += fmaxf(acc2[nt][rg] + b2n[nt], 0.0f) * w3n[nt];
#pragma unroll
    for (int mk = 1; mk < 16; mk <<= 1)
#pragma unroll
      for (int rg = 0; rg < 4; ++rg) part[rg] += __shfl_xor(part[rg], mk, 16);
    if ((lane & 15) == 0) {
      const int rb = t * 16 + (lane >> 4) * 4;
#pragma unroll
      for (int rg = 0; rg < 4; ++rg) {
        const int rr = rb + rg;
        const int b2_ = (rr * 9363) >> 18;
        const int p2  = rr - b2_ * 28;
        const size_t o = (size_t)(bb0 + b2_) * 28 + p2;
        outp[o] = dmask[o] ? (part[rg] + bias3) : -1.0e9f;
      }
    }
  }
}

extern "C" void kernel_launch(void* const* d_in, const int* in_sizes, int n_in,
                              void* d_out, int out_size, void* d_ws, size_t ws_size,
                              hipStream_t stream) {
  (void)in_sizes; (void)n_in; (void)out_size;
  const float* node = (const float*)d_in[0];
  const float* glob = (const float*)d_in[1];
  const int* dmsk   = (const int*)d_in[3];   // bool -> int32 on upload
  const float* W1 = (const float*)d_in[5];
  const float* b1 = (const float*)d_in[6];
  const float* W2 = (const float*)d_in[7];
  const float* b2 = (const float*)d_in[8];
  const float* W3 = (const float*)d_in[9];
  const float* b3 = (const float*)d_in[10];
  float* outp = (float*)d_out;

  if (ws_size >= (size_t)WS_NEED) {
    char* ws = (char*)d_ws;
    prep_weights<<<28, 1024, 0, stream>>>(W1, W2, ws);
    prep_gp<<<128, 256, 0, stream>>>(glob, b1, ws);
    docking_main<<<256, 1024, 0, stream>>>(node, dmsk, b2, W3, b3, ws, outp);
  } else {
    docking_fused<<<16384 / F_NB, F_THREADS, 0, stream>>>(node, glob, dmsk, W1, b1, W2, b2, W3, b3, outp);
  }
}